// Round 10
// baseline (51.848 us; speedup 1.0000x reference)
//
#include <hip/hip_runtime.h>

constexpr int NPTS  = 1024;   // points per batch
constexpr int NT    = 21;     // targets per batch
constexpr int KSEL  = 64;     // top-k
constexpr int BLOCK = 256;    // 4 waves per block
constexpr int PPL   = 16;     // points per lane (1024 / 64)
constexpr int NXCD  = 8;
constexpr int TPW   = 3;      // targets per wave (21 = 7 waves x 3)
constexpr int WPB   = 7;      // waves per batch b

typedef float f32x4 __attribute__((ext_vector_type(4)));

__device__ __forceinline__ unsigned key_of(float d) {
    // monotone float->uint transform (total order matching float <)
    unsigned u = __float_as_uint(d);
    return (u & 0x80000000u) ? ~u : (u | 0x80000000u);
}

__device__ __forceinline__ unsigned mbcnt64(unsigned long long m) {
    unsigned lo = __builtin_amdgcn_mbcnt_lo((unsigned)m, 0u);
    return __builtin_amdgcn_mbcnt_hi((unsigned)(m >> 32), lo);
}

__global__ __launch_bounds__(BLOCK, 2) void knn_mask_loop_kernel(
    const float* __restrict__ pc,   // (B, 1024, 3)
    const float* __restrict__ tgt,  // (B, 21, 3)
    float* __restrict__ out,        // (B, 21, 1024, 3)
    int B)
{
    const int wave = threadIdx.x >> 6;
    const int lane = threadIdx.x & 63;
    // bijective XCD swizzle (grid divisible by 8): consecutive waves (same b)
    // share an XCD's L2
    int sbid = blockIdx.x;
    if ((gridDim.x & (NXCD - 1)) == 0) {
        const int cpx = gridDim.x / NXCD;
        sbid = ((int)blockIdx.x % NXCD) * cpx + (int)blockIdx.x / NXCD;
    }
    const int gw = sbid * 4 + wave;      // 0 .. B*WPB-1
    if (gw >= B * WPB) return;           // wave-uniform
    const int b  = gw / WPB;
    const int w  = gw % WPB;             // this wave: targets 3w, 3w+1, 3w+2

    const float* base = pc + (size_t)b * (NPTS * 3);
    const f32x4* src4 = reinterpret_cast<const f32x4*>(base);

    // ---- load my 16 points ONCE; keep coords + |p|^2 in registers ----
    float px[PPL], py[PPL], pz[PPL], pn2[PPL];
    #pragma unroll
    for (int i = 0; i < PPL; ++i) {
        const float* pp = base + 3 * (64 * i + lane);
        px[i] = pp[0]; py[i] = pp[1]; pz[i] = pp[2];
        pn2[i] = px[i] * px[i] + py[i] * py[i] + pz[i] * pz[i];
    }

    // ---- task loop: stores of task t drain under keys/select of task t+1 ----
    #pragma unroll 1
    for (int tt = 0; tt < TPW; ++tt) {
        const int tq = TPW * w + tt;
        const float* tp = tgt + ((size_t)b * NT + tq) * 3;
        const float  t0 = tp[0], t1 = tp[1], t2 = tp[2];
        const float  dt = t0 * t0 + t1 * t1 + t2 * t2;

        // keys (same fp expression as rounds 5-8 -> identical ordering)
        unsigned key[PPL];
        #pragma unroll
        for (int i = 0; i < PPL; ++i) {
            const float d = dt + pn2[i]
                          - 2.0f * (t0 * px[i] + t1 * py[i] + t2 * pz[i]);
            key[i] = key_of(d);
        }

        // ---- threshold-form exact select of the KSEL-th smallest (r8) ----
        unsigned kand = key[0], kor = key[0];
        #pragma unroll
        for (int i = 1; i < PPL; ++i) { kand &= key[i]; kor |= key[i]; }
        #pragma unroll
        for (int off = 32; off > 0; off >>= 1) {
            kand &= (unsigned)__shfl_xor((int)kand, off, 64);
            kor  |= (unsigned)__shfl_xor((int)kor,  off, 64);
        }
        const unsigned dis = kor & ~kand;

        unsigned lo = 0, below = 0, want = KSEL, cls = NPTS;
        bool     early = false;
        unsigned Tsel = 0, kth = 0;
        if (dis == 0u) {
            kth = kand;
        } else {
            const int hb = 31 - __builtin_clz(dis);
            lo = (hb == 31) ? 0u : (kand & (~0u << (hb + 1)));
            for (int s = hb; s >= 0; --s) {
                const unsigned mid = lo | (1u << s);
                unsigned cnt = 0;
                #pragma unroll
                for (int i = 0; i < PPL; ++i) cnt += (key[i] < mid) ? 1u : 0u;
                unsigned c = 0;
                #pragma unroll
                for (int j = 0; j < 5; ++j)
                    c += (unsigned)__popcll(__ballot((cnt >> j) & 1u)) << j;
                const unsigned t = c - below;      // size of class-0 = [lo, mid)
                if (want <= t) { cls = t; }
                else { want -= t; below = c; lo = mid; cls -= t; }
                if (cls == want) { early = true; Tsel = lo + (1u << s); break; }
            }
            if (!early) kth = lo;
        }

        // ---- selection flags: bit i => point (64*i + lane) ----
        unsigned selmask = 0;
        if (early) {
            #pragma unroll
            for (int i = 0; i < PPL; ++i)
                if (key[i] < Tsel) selmask |= (1u << i);
        } else {
            unsigned run_tot = 0;    // stable lowest-index tie-break
            #pragma unroll
            for (int i = 0; i < PPL; ++i) {
                const bool eq = (key[i] == kth);
                const unsigned long long bal = __ballot(eq);
                const bool sel_eq = eq && (run_tot + mbcnt64(bal)) < want;
                if (key[i] < kth || sel_eq) selmask |= (1u << i);
                run_tot += (unsigned)__popcll(bal);
            }
        }

        // ---- write-once masked full-row store, restructured so no load
        // waits behind an older store (bits -> all loads -> all stores) ----
        f32x4* dst4 = reinterpret_cast<f32x4*>(out + ((size_t)b * NT + tq) * (NPTS * 3));

        unsigned cb0 = 0, cb1 = 0;   // per-chunk select bits for point q / q+1
        #pragma unroll
        for (int j = 0; j < 12; ++j) {
            const int      m  = 64 * j + lane;
            const unsigned e0 = 4u * (unsigned)m;
            const unsigned q  = e0 / 3u;
            const unsigned sm0 = (unsigned)__shfl((int)selmask, (int)(q & 63u), 64);
            const unsigned sm1 = (unsigned)__shfl((int)selmask, (int)((q + 1u) & 63u), 64);
            cb0 |= (((sm0 >> (q >> 6)) & 1u)) << j;
            cb1 |= (((sm1 >> ((q + 1u) & 63u ? (q + 1u) >> 6 : 0u)) & 1u)) << j;  // placeholder fixed below
        }
        // NOTE: the expression above for cb1 must be bit (q+1)>>6 of sm1:
        // recompute cleanly (compiler CSEs the shfls)
        cb1 = 0;
        #pragma unroll
        for (int j = 0; j < 12; ++j) {
            const int      m  = 64 * j + lane;
            const unsigned e0 = 4u * (unsigned)m;
            const unsigned q1 = e0 / 3u + 1u;
            const unsigned sm1 = (unsigned)__shfl((int)selmask, (int)(q1 & 63u), 64);
            cb1 |= ((sm1 >> (q1 >> 6)) & 1u) << j;
        }

        f32x4 g[12];
        #pragma unroll
        for (int j = 0; j < 12; ++j) g[j] = src4[64 * j + lane];

        #pragma unroll
        for (int j = 0; j < 12; ++j) {
            const int      m  = 64 * j + lane;
            const unsigned e0 = 4u * (unsigned)m;
            const unsigned q  = e0 / 3u;
            const unsigned u  = e0 - 3u * q;       // 0..2, lane-dependent
            const unsigned b0 = (cb0 >> j) & 1u;
            const unsigned b1 = (cb1 >> j) & 1u;
            f32x4 v;
            v.x = b0                    ? g[j].x : 0.0f;
            v.y = ((u == 2u) ? b1 : b0) ? g[j].y : 0.0f;
            v.z = ((u == 0u) ? b0 : b1) ? g[j].z : 0.0f;
            v.w = b1                    ? g[j].w : 0.0f;
            dst4[m] = v;
        }
        // no waitcnt: stores drain during next task's keys/select
    }
}

extern "C" void kernel_launch(void* const* d_in, const int* in_sizes, int n_in,
                              void* d_out, int out_size, void* d_ws, size_t ws_size,
                              hipStream_t stream) {
    const float* pc  = (const float*)d_in[0];  // (B,1024,3)
    const float* tgt = (const float*)d_in[1];  // (B,21,3)
    float*       out = (float*)d_out;          // (B,21,1024,3)

    const int B       = in_sizes[0] / (NPTS * 3);   // 512
    const int nwaves  = B * WPB;                     // 3584
    const int nblocks = (nwaves + 3) / 4;            // 896 (divisible by 8)

    knn_mask_loop_kernel<<<nblocks, BLOCK, 0, stream>>>(pc, tgt, out, B);
}

// Round 11
// 38.036 us; speedup vs baseline: 1.3631x; 1.3631x over previous
//
#include <hip/hip_runtime.h>

constexpr int NPTS  = 1024;   // points per batch
constexpr int NT    = 21;     // targets per batch
constexpr int KSEL  = 64;     // top-k
constexpr int BLOCK = 256;    // 4 waves, 1 wave per (b,t)
constexpr int PPL   = 16;     // points per lane (1024 / 64)
constexpr int NXCD  = 8;

typedef float f32x4 __attribute__((ext_vector_type(4)));

__device__ __forceinline__ unsigned key_of(float d) {
    // monotone float->uint transform (total order matching float <)
    unsigned u = __float_as_uint(d);
    return (u & 0x80000000u) ? ~u : (u | 0x80000000u);
}

__device__ __forceinline__ unsigned mbcnt64(unsigned long long m) {
    unsigned lo = __builtin_amdgcn_mbcnt_lo((unsigned)m, 0u);
    return __builtin_amdgcn_mbcnt_hi((unsigned)(m >> 32), lo);
}

__global__ __launch_bounds__(BLOCK) void knn_mask_stagger_kernel(
    const float* __restrict__ pc,   // (B, 1024, 3)
    const float* __restrict__ tgt,  // (B, 21, 3)
    float* __restrict__ out,        // (B, 21, 1024, 3)
    int total_bt)
{
    const int wave = threadIdx.x >> 6;
    const int lane = threadIdx.x & 63;
    // bijective XCD swizzle (gridDim.x divisible by 8)
    const int cpx  = gridDim.x / NXCD;
    const int sbid = ((int)blockIdx.x % NXCD) * cpx + (int)blockIdx.x / NXCD;
    const int bt   = sbid * 4 + wave;
    if (bt >= total_bt) return;          // wave-uniform
    const int b  = bt / NT;
    const int tq = bt % NT;

    const float* base = pc + (size_t)b * (NPTS * 3);

    // target point (wave-uniform, L1-broadcast)
    const float* tp = tgt + ((size_t)b * NT + tq) * 3;
    const float  t0 = tp[0], t1 = tp[1], t2 = tp[2];
    const float  dt = t0 * t0 + t1 * t1 + t2 * t2;

    // ---- phase 1: strided ownership (lane owns points 64*i + lane) ----
    unsigned key[PPL];
    #pragma unroll
    for (int i = 0; i < PPL; ++i) {
        const float* pp = base + 3 * (64 * i + lane);
        const float p0 = pp[0], p1 = pp[1], p2 = pp[2];
        const float d  = dt + (p0 * p0 + p1 * p1 + p2 * p2)
                            - 2.0f * (t0 * p0 + t1 * p1 + t2 * p2);
        key[i] = key_of(d);
    }

    // ---- parity time-stagger: odd waves sleep ~5k cycles (zero issue cost)
    // so while even waves store, odd waves select, and vice versa. Breaks the
    // chip-wide phase-locked select-era/store-era alternation.
    if (bt & 1) {
        #pragma unroll 1
        for (int k = 0; k < 12; ++k) __builtin_amdgcn_s_sleep(7);
    }

    // ---- phase 2: threshold-form exact select of the KSEL-th smallest (r8) ----
    unsigned kand = key[0], kor = key[0];
    #pragma unroll
    for (int i = 1; i < PPL; ++i) { kand &= key[i]; kor |= key[i]; }
    #pragma unroll
    for (int off = 32; off > 0; off >>= 1) {
        kand &= (unsigned)__shfl_xor((int)kand, off, 64);
        kor  |= (unsigned)__shfl_xor((int)kor,  off, 64);
    }
    const unsigned dis = kor & ~kand;    // bits where keys disagree

    unsigned lo = 0, below = 0, want = KSEL, cls = NPTS;
    bool     early = false;
    unsigned Tsel = 0, kth = 0;
    if (dis == 0u) {
        kth = kand;                       // all 1024 keys identical
    } else {
        const int hb = 31 - __builtin_clz(dis);
        lo = (hb == 31) ? 0u : (kand & (~0u << (hb + 1)));  // common high bits
        for (int s = hb; s >= 0; --s) {
            const unsigned mid = lo | (1u << s);
            unsigned cnt = 0;
            #pragma unroll
            for (int i = 0; i < PPL; ++i) cnt += (key[i] < mid) ? 1u : 0u;
            unsigned c = 0;               // wave total via 5-ballot decompose
            #pragma unroll
            for (int j = 0; j < 5; ++j)
                c += (unsigned)__popcll(__ballot((cnt >> j) & 1u)) << j;
            const unsigned t = c - below; // size of class-0 = [lo, mid)
            if (want <= t) { cls = t; }
            else { want -= t; below = c; lo = mid; cls -= t; }
            if (cls == want) { early = true; Tsel = lo + (1u << s); break; }
        }
        if (!early) kth = lo;
    }

    // ---- phase 3: selection flags. bit i => point (64*i + lane). ----
    unsigned selmask = 0;
    if (early) {
        #pragma unroll
        for (int i = 0; i < PPL; ++i)
            if (key[i] < Tsel) selmask |= (1u << i);
    } else {
        unsigned run_tot = 0;   // stable lowest-index ties: index = 64*i + lane
        #pragma unroll
        for (int i = 0; i < PPL; ++i) {
            const bool eq = (key[i] == kth);
            const unsigned long long bal = __ballot(eq);
            const bool sel_eq = eq && (run_tot + mbcnt64(bal)) < want;
            if (key[i] < kth || sel_eq) selmask |= (1u << i);
            run_tot += (unsigned)__popcll(bal);
        }
    }

    // ---- phase 4: write-once masked full-row store (r5), fully coalesced;
    // every output byte written exactly once -> no RFO, WRITE = 129 MB exact.
    const f32x4* src4 = reinterpret_cast<const f32x4*>(base);
    f32x4*       dst4 = reinterpret_cast<f32x4*>(out + (size_t)bt * (NPTS * 3));
    #pragma unroll
    for (int j = 0; j < 12; ++j) {
        const int      m  = 64 * j + lane;
        const f32x4    g  = src4[m];
        const unsigned e0 = 4u * (unsigned)m;
        const unsigned q  = e0 / 3u;          // first point covered by this chunk
        const unsigned u  = e0 - 3u * q;      // 0..2: chunk-start offset in point q
        const unsigned sm0 = (unsigned)__shfl((int)selmask, (int)(q & 63u), 64);
        const unsigned sm1 = (unsigned)__shfl((int)selmask, (int)((q + 1u) & 63u), 64);
        const unsigned b0  = (sm0 >> (q >> 6)) & 1u;
        const unsigned b1  = (sm1 >> ((q + 1u) >> 6)) & 1u;
        f32x4 v;
        v.x = b0                    ? g.x : 0.0f;   // elem e0   -> point q
        v.y = ((u == 2u) ? b1 : b0) ? g.y : 0.0f;   // elem e0+1
        v.z = ((u == 0u) ? b0 : b1) ? g.z : 0.0f;   // elem e0+2
        v.w = b1                    ? g.w : 0.0f;   // elem e0+3 -> point q+1
        dst4[m] = v;
    }
}

extern "C" void kernel_launch(void* const* d_in, const int* in_sizes, int n_in,
                              void* d_out, int out_size, void* d_ws, size_t ws_size,
                              hipStream_t stream) {
    const float* pc  = (const float*)d_in[0];  // (B,1024,3)
    const float* tgt = (const float*)d_in[1];  // (B,21,3)
    float*       out = (float*)d_out;          // (B,21,1024,3)

    const int B        = in_sizes[0] / (NPTS * 3);   // 512
    const int total_bt = B * NT;                      // 10752
    const int nblocks  = (total_bt + 3) / 4;          // 2688 (divisible by 8)

    knn_mask_stagger_kernel<<<nblocks, BLOCK, 0, stream>>>(pc, tgt, out, total_bt);
}